// Round 5
// baseline (4235.971 us; speedup 1.0000x reference)
//
#include <hip/hip_runtime.h>
#include <hip/hip_bf16.h>

// ---------------------------------------------------------------------------
// GCN forward: bucket-partition CSR-lite build -> 3x (GEMM w/ fused dis-scale
// + bf16 store -> bucket-LDS-accumulate aggregate) -> pool fused into agg3 ->
// FC head.
// hs = dis[n]*h[n] in bf16; agg[n] = dis[n]*(sum hs[s] + hs[n]) + b.
// k_agg: one block per 128-node bucket; 128x64 fp32 accumulator in LDS
// (stride 65 for bank spread); gathers hs[src] ushort4 (4 edges/VMEM instr),
// LDS atomicAdd per channel. No per-node sort, no colidx.
// ---------------------------------------------------------------------------

#define NBLK 256        // partition blocks
#define MAXNB 1024      // max buckets supported (N <= 131072)
#define S_ACC 65        // LDS accumulator row stride (pad for bank spread)

__device__ __forceinline__ float bf2f(unsigned short v) {
    return __uint_as_float(((unsigned int)v) << 16);
}
__device__ __forceinline__ unsigned short f2bf(float x) {
    __hip_bfloat16 b = __float2bfloat16(x);  // round-to-nearest
    return *(unsigned short*)&b;
}
__device__ __forceinline__ float4 bf4(ushort4 v) {
    return make_float4(bf2f(v.x), bf2f(v.y), bf2f(v.z), bf2f(v.w));
}

// P1: per-block bucket histogram (int4-vectorized edge reads).
__global__ __launch_bounds__(256) void k_hist(const int* __restrict__ dst,
                                              int* __restrict__ blockhist,
                                              int E, int chunk, int nb) {
    __shared__ int h[MAXNB];
    int b = blockIdx.x, t = threadIdx.x;
    for (int j = t; j < nb; j += 256) h[j] = 0;
    __syncthreads();
    int lo = b * chunk, hi = min(lo + chunk, E);
    int m = hi - lo;
    int nv = m >> 2;
    const int4* d4 = (const int4*)(dst + lo);
    for (int i = t; i < nv; i += 256) {
        int4 v = d4[i];
        atomicAdd(&h[v.x >> 7], 1);
        atomicAdd(&h[v.y >> 7], 1);
        atomicAdd(&h[v.z >> 7], 1);
        atomicAdd(&h[v.w >> 7], 1);
    }
    for (int i = lo + (nv << 2) + t; i < hi; i += 256) atomicAdd(&h[dst[i] >> 7], 1);
    __syncthreads();
    for (int j = t; j < nb; j += 256) blockhist[j * NBLK + b] = h[j];
}

// P2a: per-bucket exclusive scan over blocks (in place); btotal[j] = total.
__global__ __launch_bounds__(256) void k_bscan(int* __restrict__ blockhist,
                                               int* __restrict__ btotal) {
    __shared__ int sm[256];
    int j = blockIdx.x, t = threadIdx.x;
    int v = blockhist[j * NBLK + t];
    sm[t] = v;
    __syncthreads();
    for (int d = 1; d < 256; d <<= 1) {
        int u = (t >= d) ? sm[t - d] : 0;
        __syncthreads();
        sm[t] += u;
        __syncthreads();
    }
    blockhist[j * NBLK + t] = sm[t] - v;
    if (t == 255) btotal[j] = sm[255];
}

// P2b: single-block exclusive scan of bucket totals -> starts[0..nb].
__global__ __launch_bounds__(256) void k_sscan(const int* __restrict__ btotal,
                                               int* __restrict__ starts, int nb) {
    __shared__ int sm[256];
    int t = threadIdx.x;
    int base = t * 4;
    int v0 = (base + 0 < nb) ? btotal[base + 0] : 0;
    int v1 = (base + 1 < nb) ? btotal[base + 1] : 0;
    int v2 = (base + 2 < nb) ? btotal[base + 2] : 0;
    int v3 = (base + 3 < nb) ? btotal[base + 3] : 0;
    int tsum = v0 + v1 + v2 + v3;
    sm[t] = tsum;
    __syncthreads();
    for (int d = 1; d < 256; d <<= 1) {
        int u = (t >= d) ? sm[t - d] : 0;
        __syncthreads();
        sm[t] += u;
        __syncthreads();
    }
    int excl = sm[t] - tsum;
    if (base + 0 < nb) starts[base + 0] = excl;
    if (base + 1 < nb) starts[base + 1] = excl + v0;
    if (base + 2 < nb) starts[base + 2] = excl + v0 + v1;
    if (base + 3 < nb) starts[base + 3] = excl + v0 + v1 + v2;
    if (t == 255) starts[nb] = sm[255];
}

// P3: partition edges into bucket regions. epart = src | (dst&127)<<17.
__global__ __launch_bounds__(256) void k_part(const int* __restrict__ src,
                                              const int* __restrict__ dst,
                                              const int* __restrict__ blockhist,
                                              const int* __restrict__ starts,
                                              unsigned int* __restrict__ epart,
                                              int E, int chunk, int nb) {
    __shared__ int cur[MAXNB];
    int b = blockIdx.x, t = threadIdx.x;
    for (int j = t; j < nb; j += 256) cur[j] = starts[j] + blockhist[j * NBLK + b];
    __syncthreads();
    int lo = b * chunk, hi = min(lo + chunk, E);
    int m = hi - lo;
    int nv = m >> 2;
    const int4* d4 = (const int4*)(dst + lo);
    const int4* s4 = (const int4*)(src + lo);
    for (int i = t; i < nv; i += 256) {
        int4 d = d4[i];
        int4 s = s4[i];
        int p;
        p = atomicAdd(&cur[d.x >> 7], 1); epart[p] = (unsigned int)s.x | ((unsigned int)(d.x & 127) << 17);
        p = atomicAdd(&cur[d.y >> 7], 1); epart[p] = (unsigned int)s.y | ((unsigned int)(d.y & 127) << 17);
        p = atomicAdd(&cur[d.z >> 7], 1); epart[p] = (unsigned int)s.z | ((unsigned int)(d.z & 127) << 17);
        p = atomicAdd(&cur[d.w >> 7], 1); epart[p] = (unsigned int)s.w | ((unsigned int)(d.w & 127) << 17);
    }
    for (int i = lo + (nv << 2) + t; i < hi; i += 256) {
        int d = dst[i];
        int pos = atomicAdd(&cur[d >> 7], 1);
        epart[pos] = (unsigned int)src[i] | ((unsigned int)(d & 127) << 17);
    }
}

// P4: per-bucket degree -> dis only (no sort needed anymore).
__global__ __launch_bounds__(256) void k_bdeg(const unsigned int* __restrict__ epart,
                                              const int* __restrict__ starts,
                                              float* __restrict__ dis, int N) {
    __shared__ int cnt[128];
    int j = blockIdx.x, t = threadIdx.x;
    int n0 = j << 7;
    int nn = min(128, N - n0);
    int s = starts[j], e = starts[j + 1];
    if (t < 128) cnt[t] = 0;
    __syncthreads();
    for (int i = s + t; i < e; i += 256) atomicAdd(&cnt[epart[i] >> 17], 1);
    __syncthreads();
    if (t < nn) dis[n0 + t] = rsqrtf((float)cnt[t] + 1.0f);
}

// C[64 x 64] per block = A[64 x K] * W[K x 64]. fp32 accumulate, epilogue
// scales row by dis[row] and stores bf16.
template <int K>
__global__ __launch_bounds__(256) void k_gemm(const float* __restrict__ A,
                                              const float* __restrict__ W,
                                              const float* __restrict__ dis,
                                              unsigned short* __restrict__ hs,
                                              int N) {
    __shared__ float As[K * 64];
    __shared__ float Ws[K * 64];
    const int tid = threadIdx.x;
    const int r0 = blockIdx.x * 64;

    {
        const float4* Wv = (const float4*)W;
        float4* Wsv = (float4*)Ws;
#pragma unroll
        for (int i = 0; i < (K * 64 / 4) / 256; ++i)
            Wsv[tid + i * 256] = Wv[tid + i * 256];
    }
    {
#pragma unroll
        for (int i = 0; i < (64 * (K / 4)) / 256; ++i) {
            int idx = tid + i * 256;
            int row = idx / (K / 4);
            int kq = idx % (K / 4);
            int gr = r0 + row;
            float4 a = (gr < N) ? ((const float4*)(A + (size_t)gr * K))[kq]
                                : make_float4(0.f, 0.f, 0.f, 0.f);
            int slot = ((row >> 2) ^ (kq & 15));
            float* p = &As[(kq * 4) * 64 + slot * 4 + (row & 3)];
            p[0 * 64] = a.x;
            p[1 * 64] = a.y;
            p[2 * 64] = a.z;
            p[3 * 64] = a.w;
        }
    }
    __syncthreads();

    const int trow = tid >> 4;
    const int tcol = tid & 15;
    float acc[4][4] = {};
#pragma unroll 4
    for (int k = 0; k < K; ++k) {
        int slot = trow ^ ((k >> 2) & 15);
        float4 a = *(const float4*)&As[k * 64 + slot * 4];
        float4 b = *(const float4*)&Ws[k * 64 + tcol * 4];
        acc[0][0] += a.x * b.x; acc[0][1] += a.x * b.y; acc[0][2] += a.x * b.z; acc[0][3] += a.x * b.w;
        acc[1][0] += a.y * b.x; acc[1][1] += a.y * b.y; acc[1][2] += a.y * b.z; acc[1][3] += a.y * b.w;
        acc[2][0] += a.z * b.x; acc[2][1] += a.z * b.y; acc[2][2] += a.z * b.z; acc[2][3] += a.z * b.w;
        acc[3][0] += a.w * b.x; acc[3][1] += a.w * b.y; acc[3][2] += a.w * b.z; acc[3][3] += a.w * b.w;
    }
#pragma unroll
    for (int i = 0; i < 4; ++i) {
        int gr = r0 + trow * 4 + i;
        if (gr < N) {
            float dn = dis[gr];
            ushort4 v;
            v.x = f2bf(acc[i][0] * dn);
            v.y = f2bf(acc[i][1] * dn);
            v.z = f2bf(acc[i][2] * dn);
            v.w = f2bf(acc[i][3] * dn);
            *(ushort4*)&hs[(size_t)gr * 64 + tcol * 4] = v;
        }
    }
}

// Aggregate: one block per bucket. LDS acc[128][64] (stride 65). Each wave
// processes a contiguous quarter of the bucket's edges; lane = eslot(0..3) x
// chquad(0..15); ushort4 gathers move 4 edges per VMEM instr; per-channel
// LDS atomicAdd. Epilogue: scale+bias(+relu) -> obuf, or fused mean-pool.
template <int RELU, int POOL>
__global__ __launch_bounds__(256) void k_agg(const unsigned short* __restrict__ hs,
                                             const int* __restrict__ starts,
                                             const unsigned int* __restrict__ epart,
                                             const float* __restrict__ dis,
                                             const float* __restrict__ bias,
                                             const int* __restrict__ batch,
                                             float* __restrict__ out,
                                             float* __restrict__ psum,
                                             float* __restrict__ pcnt, int N) {
    __shared__ float acc[128 * S_ACC];
    int j = blockIdx.x, t = threadIdx.x;
    int n0 = j << 7;
    int nn = min(128, N - n0);
    int s = starts[j], e = starts[j + 1];
    int m = e - s;
    for (int i = t; i < 128 * S_ACC; i += 256) acc[i] = 0.f;
    __syncthreads();

    int w = t >> 6, lane = t & 63;
    int eslot = lane >> 4;   // 0..3
    int cq = lane & 15;      // channel quad
    const unsigned int* ep = epart + s;

    int qsz = (m + 3) >> 2;
    int lo = w * qsz;
    int hi = min(lo + qsz, m);

    int i = lo;
    for (; i + 16 <= hi; i += 16) {
        unsigned int p0 = ep[i + 0 + eslot];
        unsigned int p1 = ep[i + 4 + eslot];
        unsigned int p2 = ep[i + 8 + eslot];
        unsigned int p3 = ep[i + 12 + eslot];
        ushort4 a0 = *(const ushort4*)&hs[(size_t)(p0 & 0x1FFFF) * 64 + cq * 4];
        ushort4 a1 = *(const ushort4*)&hs[(size_t)(p1 & 0x1FFFF) * 64 + cq * 4];
        ushort4 a2 = *(const ushort4*)&hs[(size_t)(p2 & 0x1FFFF) * 64 + cq * 4];
        ushort4 a3 = *(const ushort4*)&hs[(size_t)(p3 & 0x1FFFF) * 64 + cq * 4];
        float4 f0 = bf4(a0), f1 = bf4(a1), f2 = bf4(a2), f3 = bf4(a3);
        float* q0 = &acc[(p0 >> 17) * S_ACC + cq * 4];
        float* q1 = &acc[(p1 >> 17) * S_ACC + cq * 4];
        float* q2 = &acc[(p2 >> 17) * S_ACC + cq * 4];
        float* q3 = &acc[(p3 >> 17) * S_ACC + cq * 4];
        atomicAdd(q0 + 0, f0.x); atomicAdd(q0 + 1, f0.y); atomicAdd(q0 + 2, f0.z); atomicAdd(q0 + 3, f0.w);
        atomicAdd(q1 + 0, f1.x); atomicAdd(q1 + 1, f1.y); atomicAdd(q1 + 2, f1.z); atomicAdd(q1 + 3, f1.w);
        atomicAdd(q2 + 0, f2.x); atomicAdd(q2 + 1, f2.y); atomicAdd(q2 + 2, f2.z); atomicAdd(q2 + 3, f2.w);
        atomicAdd(q3 + 0, f3.x); atomicAdd(q3 + 1, f3.y); atomicAdd(q3 + 2, f3.z); atomicAdd(q3 + 3, f3.w);
    }
    for (; i < hi; i += 4) {
        int idx = i + eslot;
        if (idx < hi) {
            unsigned int p = ep[idx];
            ushort4 a = *(const ushort4*)&hs[(size_t)(p & 0x1FFFF) * 64 + cq * 4];
            float4 f = bf4(a);
            float* q = &acc[(p >> 17) * S_ACC + cq * 4];
            atomicAdd(q + 0, f.x); atomicAdd(q + 1, f.y);
            atomicAdd(q + 2, f.z); atomicAdd(q + 3, f.w);
        }
    }
    __syncthreads();

    // Epilogue: wave w handles rows w*32 .. w*32+31 (lane = channel).
    int rlim = min(w * 32 + 32, nn);
    float bl = bias[lane];
    if (POOL) {
        float racc = 0.f;
        float rcnt = 0.f;
        int curg = -1;
        for (int r = w * 32; r < rlim; ++r) {
            int n = n0 + r;
            float a = acc[r * S_ACC + lane];
            float self = bf2f(hs[(size_t)n * 64 + lane]);
            float v = dis[n] * (a + self) + bl;
            int g = batch[n];
            if (g != curg) {
                if (curg >= 0) {
                    atomicAdd(&psum[curg * 64 + lane], racc);
                    if (lane == 0) atomicAdd(&pcnt[curg], rcnt);
                }
                curg = g;
                racc = 0.f;
                rcnt = 0.f;
            }
            racc += v;
            rcnt += 1.f;
        }
        if (curg >= 0) {
            atomicAdd(&psum[curg * 64 + lane], racc);
            if (lane == 0) atomicAdd(&pcnt[curg], rcnt);
        }
    } else {
        for (int r = w * 32; r < rlim; ++r) {
            int n = n0 + r;
            float a = acc[r * S_ACC + lane];
            float self = bf2f(hs[(size_t)n * 64 + lane]);
            float v = dis[n] * (a + self) + bl;
            if (RELU) v = fmaxf(v, 0.f);
            out[(size_t)n * 64 + lane] = v;
        }
    }
}

__global__ __launch_bounds__(64) void k_head(const float* __restrict__ psum,
                                             const float* __restrict__ pcnt,
                                             const float* __restrict__ Wfc,
                                             const float* __restrict__ bfc,
                                             float* __restrict__ out) {
    __shared__ float p[64];
    int g = blockIdx.x, t = threadIdx.x;
    float cnt = fmaxf(pcnt[g], 1.0f);
    p[t] = psum[g * 64 + t] / cnt;
    __syncthreads();
    if (t < 10) {
        float acc = bfc[t];
#pragma unroll
        for (int hh = 0; hh < 64; ++hh) acc += p[hh] * Wfc[hh * 10 + t];
        out[g * 10 + t] = acc;
    }
}

extern "C" void kernel_launch(void* const* d_in, const int* in_sizes, int n_in,
                              void* d_out, int out_size, void* d_ws, size_t ws_size,
                              hipStream_t stream) {
    const float* x = (const float*)d_in[0];
    const int* eidx = (const int*)d_in[1];
    const int* batch = (const int*)d_in[2];
    const float* W1 = (const float*)d_in[3];
    const float* b1 = (const float*)d_in[4];
    const float* W2 = (const float*)d_in[5];
    const float* b2 = (const float*)d_in[6];
    const float* W3 = (const float*)d_in[7];
    const float* b3 = (const float*)d_in[8];
    const float* Wfc = (const float*)d_in[9];
    const float* bfc = (const float*)d_in[10];
    float* out = (float*)d_out;

    const int N = in_sizes[0] / 128;  // 100000
    const int E = in_sizes[1] / 2;    // 3200000
    const int G = out_size / 10;      // 512
    const int NB = (N + 127) / 128;   // 782
    const int chunk = (E + NBLK - 1) / NBLK;

    char* ws = (char*)d_ws;
    size_t off = 0;
    auto alloc = [&](size_t bytes) -> char* {
        char* p = ws + off;
        off = (off + bytes + 511) & ~(size_t)511;
        return p;
    };
    float* dis = (float*)alloc((size_t)N * 4);
    int* starts = (int*)alloc((size_t)(MAXNB + 1) * 4);
    int* btotal = (int*)alloc((size_t)MAXNB * 4);
    int* blockhist = (int*)alloc((size_t)NB * NBLK * 4);
    unsigned int* epart = (unsigned int*)alloc((size_t)E * 4);
    unsigned short* hsb = (unsigned short*)alloc((size_t)N * 64 * 2);  // bf16
    float* obuf = (float*)alloc((size_t)N * 64 * 4);
    float* psum = (float*)alloc((size_t)G * 64 * 4 + (size_t)G * 4);
    float* pcnt = psum + (size_t)G * 64;

    hipMemsetAsync(psum, 0, (size_t)G * 64 * 4 + (size_t)G * 4, stream);

    const int* esrc = eidx;
    const int* edst = eidx + E;

    k_hist<<<NBLK, 256, 0, stream>>>(edst, blockhist, E, chunk, NB);
    k_bscan<<<NB, 256, 0, stream>>>(blockhist, btotal);
    k_sscan<<<1, 256, 0, stream>>>(btotal, starts, NB);
    k_part<<<NBLK, 256, 0, stream>>>(esrc, edst, blockhist, starts, epart, E, chunk, NB);
    k_bdeg<<<NB, 256, 0, stream>>>(epart, starts, dis, N);

    int gblk = (N + 63) / 64;
    k_gemm<128><<<gblk, 256, 0, stream>>>(x, W1, dis, hsb, N);
    k_agg<1, 0><<<NB, 256, 0, stream>>>(hsb, starts, epart, dis, b1, batch, obuf, psum, pcnt, N);
    k_gemm<64><<<gblk, 256, 0, stream>>>(obuf, W2, dis, hsb, N);
    k_agg<1, 0><<<NB, 256, 0, stream>>>(hsb, starts, epart, dis, b2, batch, obuf, psum, pcnt, N);
    k_gemm<64><<<gblk, 256, 0, stream>>>(obuf, W3, dis, hsb, N);
    k_agg<0, 1><<<NB, 256, 0, stream>>>(hsb, starts, epart, dis, b3, batch, obuf, psum, pcnt, N);

    k_head<<<G, 64, 0, stream>>>(psum, pcnt, Wfc, bfc, out);
}

// Round 6
// 427.941 us; speedup vs baseline: 9.8985x; 9.8985x over previous
//
#include <hip/hip_runtime.h>
#include <hip/hip_bf16.h>

// ---------------------------------------------------------------------------
// GCN forward: hierarchical atomic-free CSR build (with 16-padded per-node
// edge lists) -> 3x (GEMM w/ fused dis-scale + bf16 store -> padded colidx
// gather aggregate) -> run-fused mean pool -> FC head.
// hs = dis[n]*h[n] in bf16 with a zeroed dummy row at index N; every node's
// colidx list is padded to a multiple of 16 with src=N, so k_agg's loop is
// branchless 16/32-edge blocks with 4-8 outstanding gathers.
// NOTE (R5 lesson): NO float LDS atomics anywhere — they lower to CAS loops
// on gfx950 and cost ~20x (measured 1341us vs 67us).
// ---------------------------------------------------------------------------

#define NBLK 256        // partition blocks
#define MAXNB 1024      // max buckets supported (N <= 131072)
#define FCAP 4608       // LDS edge-staging capacity in k_fine
#define BPAD 2048       // per-bucket colidx padding slack (128 nodes * 15 max)

__device__ __forceinline__ float bf2f(unsigned short v) {
    return __uint_as_float(((unsigned int)v) << 16);
}
__device__ __forceinline__ unsigned short f2bf(float x) {
    __hip_bfloat16 b = __float2bfloat16(x);  // round-to-nearest
    return *(unsigned short*)&b;
}
__device__ __forceinline__ float4 bf4(ushort4 v) {
    return make_float4(bf2f(v.x), bf2f(v.y), bf2f(v.z), bf2f(v.w));
}

// P1: per-block bucket histogram (int4-vectorized edge reads).
__global__ __launch_bounds__(256) void k_hist(const int* __restrict__ dst,
                                              int* __restrict__ blockhist,
                                              int E, int chunk, int nb) {
    __shared__ int h[MAXNB];
    int b = blockIdx.x, t = threadIdx.x;
    for (int j = t; j < nb; j += 256) h[j] = 0;
    __syncthreads();
    int lo = b * chunk, hi = min(lo + chunk, E);
    int m = hi - lo;
    int nv = m >> 2;
    const int4* d4 = (const int4*)(dst + lo);
    for (int i = t; i < nv; i += 256) {
        int4 v = d4[i];
        atomicAdd(&h[v.x >> 7], 1);
        atomicAdd(&h[v.y >> 7], 1);
        atomicAdd(&h[v.z >> 7], 1);
        atomicAdd(&h[v.w >> 7], 1);
    }
    for (int i = lo + (nv << 2) + t; i < hi; i += 256) atomicAdd(&h[dst[i] >> 7], 1);
    __syncthreads();
    for (int j = t; j < nb; j += 256) blockhist[j * NBLK + b] = h[j];
}

// P2a: per-bucket exclusive scan over blocks (in place); btotal[j] = total.
__global__ __launch_bounds__(256) void k_bscan(int* __restrict__ blockhist,
                                               int* __restrict__ btotal) {
    __shared__ int sm[256];
    int j = blockIdx.x, t = threadIdx.x;
    int v = blockhist[j * NBLK + t];
    sm[t] = v;
    __syncthreads();
    for (int d = 1; d < 256; d <<= 1) {
        int u = (t >= d) ? sm[t - d] : 0;
        __syncthreads();
        sm[t] += u;
        __syncthreads();
    }
    blockhist[j * NBLK + t] = sm[t] - v;
    if (t == 255) btotal[j] = sm[255];
}

// P2b: single-block exclusive scan of bucket totals -> starts[0..nb].
__global__ __launch_bounds__(256) void k_sscan(const int* __restrict__ btotal,
                                               int* __restrict__ starts, int nb) {
    __shared__ int sm[256];
    int t = threadIdx.x;
    int base = t * 4;
    int v0 = (base + 0 < nb) ? btotal[base + 0] : 0;
    int v1 = (base + 1 < nb) ? btotal[base + 1] : 0;
    int v2 = (base + 2 < nb) ? btotal[base + 2] : 0;
    int v3 = (base + 3 < nb) ? btotal[base + 3] : 0;
    int tsum = v0 + v1 + v2 + v3;
    sm[t] = tsum;
    __syncthreads();
    for (int d = 1; d < 256; d <<= 1) {
        int u = (t >= d) ? sm[t - d] : 0;
        __syncthreads();
        sm[t] += u;
        __syncthreads();
    }
    int excl = sm[t] - tsum;
    if (base + 0 < nb) starts[base + 0] = excl;
    if (base + 1 < nb) starts[base + 1] = excl + v0;
    if (base + 2 < nb) starts[base + 2] = excl + v0 + v1;
    if (base + 3 < nb) starts[base + 3] = excl + v0 + v1 + v2;
    if (t == 255) starts[nb] = sm[255];
}

// P3: partition edges into bucket regions. epart = src | (dst&127)<<17.
__global__ __launch_bounds__(256) void k_part(const int* __restrict__ src,
                                              const int* __restrict__ dst,
                                              const int* __restrict__ blockhist,
                                              const int* __restrict__ starts,
                                              unsigned int* __restrict__ epart,
                                              int E, int chunk, int nb) {
    __shared__ int cur[MAXNB];
    int b = blockIdx.x, t = threadIdx.x;
    for (int j = t; j < nb; j += 256) cur[j] = starts[j] + blockhist[j * NBLK + b];
    __syncthreads();
    int lo = b * chunk, hi = min(lo + chunk, E);
    int m = hi - lo;
    int nv = m >> 2;
    const int4* d4 = (const int4*)(dst + lo);
    const int4* s4 = (const int4*)(src + lo);
    for (int i = t; i < nv; i += 256) {
        int4 d = d4[i];
        int4 s = s4[i];
        int p;
        p = atomicAdd(&cur[d.x >> 7], 1); epart[p] = (unsigned int)s.x | ((unsigned int)(d.x & 127) << 17);
        p = atomicAdd(&cur[d.y >> 7], 1); epart[p] = (unsigned int)s.y | ((unsigned int)(d.y & 127) << 17);
        p = atomicAdd(&cur[d.z >> 7], 1); epart[p] = (unsigned int)s.z | ((unsigned int)(d.z & 127) << 17);
        p = atomicAdd(&cur[d.w >> 7], 1); epart[p] = (unsigned int)s.w | ((unsigned int)(d.w & 127) << 17);
    }
    for (int i = lo + (nv << 2) + t; i < hi; i += 256) {
        int d = dst[i];
        int pos = atomicAdd(&cur[d >> 7], 1);
        epart[pos] = (unsigned int)src[i] | ((unsigned int)(d & 127) << 17);
    }
}

// P4: per-bucket fine sort with padded per-node lists. Emits deg, padded
// rowptr, dis, colidx (each node's list padded to x16 with dummy src = N).
__global__ __launch_bounds__(256) void k_fine(const unsigned int* __restrict__ epart,
                                              const int* __restrict__ starts,
                                              int* __restrict__ deg,
                                              int* __restrict__ rowptr,
                                              float* __restrict__ dis,
                                              int* __restrict__ colidx, int N) {
    __shared__ unsigned int eb[FCAP];
    __shared__ int cnt[128], sc[128], cur[128];
    int j = blockIdx.x, t = threadIdx.x;
    int n0 = j << 7;
    int nn = min(128, N - n0);
    int s = starts[j], e = starts[j + 1];
    int m = e - s;
    int pbase = s + j * BPAD;  // padded bucket start in colidx
    if (t < 128) cnt[t] = 0;
    __syncthreads();
    for (int i = t; i < m; i += 256) {
        unsigned int p = epart[s + i];
        if (i < FCAP) eb[i] = p;
        atomicAdd(&cnt[p >> 17], 1);
    }
    __syncthreads();
    int pcv = 0;
    if (t < 128) { pcv = (cnt[t] + 15) & ~15; sc[t] = pcv; }
    __syncthreads();
    for (int d = 1; d < 128; d <<= 1) {
        int u = (t < 128 && t >= d) ? sc[t - d] : 0;
        __syncthreads();
        if (t < 128) sc[t] += u;
        __syncthreads();
    }
    if (t < nn) {
        int c = cnt[t];
        int rp = pbase + sc[t] - pcv;  // exclusive padded offset
        deg[n0 + t] = c;
        rowptr[n0 + t] = rp;
        dis[n0 + t] = rsqrtf((float)c + 1.0f);
        cur[t] = rp;
    }
    __syncthreads();
    for (int i = t; i < m; i += 256) {
        unsigned int p = (i < FCAP) ? eb[i] : epart[s + i];
        int pos = atomicAdd(&cur[p >> 17], 1);
        colidx[pos] = (int)(p & 0x1FFFF);
    }
    __syncthreads();
    if (t < nn) {
        int endp = rowptr[n0 + t] + ((cnt[t] + 15) & ~15);
        for (int q = cur[t]; q < endp; ++q) colidx[q] = N;  // dummy row
    }
}

// C[64 x 64] per block = A[64 x K] * W[K x 64]. fp32 accumulate, epilogue
// scales row by dis[row] and stores bf16.
template <int K>
__global__ __launch_bounds__(256) void k_gemm(const float* __restrict__ A,
                                              const float* __restrict__ W,
                                              const float* __restrict__ dis,
                                              unsigned short* __restrict__ hs,
                                              int N) {
    __shared__ float As[K * 64];
    __shared__ float Ws[K * 64];
    const int tid = threadIdx.x;
    const int r0 = blockIdx.x * 64;

    {
        const float4* Wv = (const float4*)W;
        float4* Wsv = (float4*)Ws;
#pragma unroll
        for (int i = 0; i < (K * 64 / 4) / 256; ++i)
            Wsv[tid + i * 256] = Wv[tid + i * 256];
    }
    {
#pragma unroll
        for (int i = 0; i < (64 * (K / 4)) / 256; ++i) {
            int idx = tid + i * 256;
            int row = idx / (K / 4);
            int kq = idx % (K / 4);
            int gr = r0 + row;
            float4 a = (gr < N) ? ((const float4*)(A + (size_t)gr * K))[kq]
                                : make_float4(0.f, 0.f, 0.f, 0.f);
            int slot = ((row >> 2) ^ (kq & 15));
            float* p = &As[(kq * 4) * 64 + slot * 4 + (row & 3)];
            p[0 * 64] = a.x;
            p[1 * 64] = a.y;
            p[2 * 64] = a.z;
            p[3 * 64] = a.w;
        }
    }
    __syncthreads();

    const int trow = tid >> 4;
    const int tcol = tid & 15;
    float acc[4][4] = {};
#pragma unroll 4
    for (int k = 0; k < K; ++k) {
        int slot = trow ^ ((k >> 2) & 15);
        float4 a = *(const float4*)&As[k * 64 + slot * 4];
        float4 b = *(const float4*)&Ws[k * 64 + tcol * 4];
        acc[0][0] += a.x * b.x; acc[0][1] += a.x * b.y; acc[0][2] += a.x * b.z; acc[0][3] += a.x * b.w;
        acc[1][0] += a.y * b.x; acc[1][1] += a.y * b.y; acc[1][2] += a.y * b.z; acc[1][3] += a.y * b.w;
        acc[2][0] += a.z * b.x; acc[2][1] += a.z * b.y; acc[2][2] += a.z * b.z; acc[2][3] += a.z * b.w;
        acc[3][0] += a.w * b.x; acc[3][1] += a.w * b.y; acc[3][2] += a.w * b.z; acc[3][3] += a.w * b.w;
    }
#pragma unroll
    for (int i = 0; i < 4; ++i) {
        int gr = r0 + trow * 4 + i;
        if (gr < N) {
            float dn = dis[gr];
            ushort4 v;
            v.x = f2bf(acc[i][0] * dn);
            v.y = f2bf(acc[i][1] * dn);
            v.z = f2bf(acc[i][2] * dn);
            v.w = f2bf(acc[i][3] * dn);
            *(ushort4*)&hs[(size_t)gr * 64 + tcol * 4] = v;
        }
    }
}

// One wave per node. lane = eslot(0..3) x chquad(0..15). Edge lists padded to
// x16 with dummy src=N (zero row): branchless 16/32-edge blocks, 4-8
// outstanding gathers. Butterfly-reduce edge slots.
template <int RELU>
__global__ __launch_bounds__(256) void k_agg(const unsigned short* __restrict__ hs,
                                             const int* __restrict__ rowptr,
                                             const int* __restrict__ deg,
                                             const int* __restrict__ colidx,
                                             const float* __restrict__ dis,
                                             const float* __restrict__ bias,
                                             float* __restrict__ out, int N) {
    int node = blockIdx.x * 4 + (threadIdx.x >> 6);
    if (node >= N) return;
    int lane = threadIdx.x & 63;
    int eslot = lane >> 4;   // 0..3
    int cq = lane & 15;      // channel quad

    int start = rowptr[node];
    int cnt = deg[node];
    int pcnt = (cnt + 15) & ~15;
    const int* ci = colidx + start + eslot;
    float4 acc = make_float4(0.f, 0.f, 0.f, 0.f);

    int i = 0;
    if (pcnt & 16) {
        int s0 = ci[0], s1 = ci[4], s2 = ci[8], s3 = ci[12];
        ushort4 a0 = *(const ushort4*)&hs[(size_t)s0 * 64 + cq * 4];
        ushort4 a1 = *(const ushort4*)&hs[(size_t)s1 * 64 + cq * 4];
        ushort4 a2 = *(const ushort4*)&hs[(size_t)s2 * 64 + cq * 4];
        ushort4 a3 = *(const ushort4*)&hs[(size_t)s3 * 64 + cq * 4];
        float4 f0 = bf4(a0), f1 = bf4(a1), f2 = bf4(a2), f3 = bf4(a3);
        acc.x += f0.x + f1.x + f2.x + f3.x;
        acc.y += f0.y + f1.y + f2.y + f3.y;
        acc.z += f0.z + f1.z + f2.z + f3.z;
        acc.w += f0.w + f1.w + f2.w + f3.w;
        i = 16;
    }
    for (; i < pcnt; i += 32) {
        int s0 = ci[i + 0],  s1 = ci[i + 4],  s2 = ci[i + 8],  s3 = ci[i + 12];
        int s4 = ci[i + 16], s5 = ci[i + 20], s6 = ci[i + 24], s7 = ci[i + 28];
        ushort4 a0 = *(const ushort4*)&hs[(size_t)s0 * 64 + cq * 4];
        ushort4 a1 = *(const ushort4*)&hs[(size_t)s1 * 64 + cq * 4];
        ushort4 a2 = *(const ushort4*)&hs[(size_t)s2 * 64 + cq * 4];
        ushort4 a3 = *(const ushort4*)&hs[(size_t)s3 * 64 + cq * 4];
        ushort4 a4 = *(const ushort4*)&hs[(size_t)s4 * 64 + cq * 4];
        ushort4 a5 = *(const ushort4*)&hs[(size_t)s5 * 64 + cq * 4];
        ushort4 a6 = *(const ushort4*)&hs[(size_t)s6 * 64 + cq * 4];
        ushort4 a7 = *(const ushort4*)&hs[(size_t)s7 * 64 + cq * 4];
        float4 f0 = bf4(a0), f1 = bf4(a1), f2 = bf4(a2), f3 = bf4(a3);
        float4 f4 = bf4(a4), f5 = bf4(a5), f6 = bf4(a6), f7 = bf4(a7);
        acc.x += (f0.x + f1.x) + (f2.x + f3.x) + (f4.x + f5.x) + (f6.x + f7.x);
        acc.y += (f0.y + f1.y) + (f2.y + f3.y) + (f4.y + f5.y) + (f6.y + f7.y);
        acc.z += (f0.z + f1.z) + (f2.z + f3.z) + (f4.z + f5.z) + (f6.z + f7.z);
        acc.w += (f0.w + f1.w) + (f2.w + f3.w) + (f4.w + f5.w) + (f6.w + f7.w);
    }

    acc.x += __shfl_xor(acc.x, 16, 64);
    acc.y += __shfl_xor(acc.y, 16, 64);
    acc.z += __shfl_xor(acc.z, 16, 64);
    acc.w += __shfl_xor(acc.w, 16, 64);
    acc.x += __shfl_xor(acc.x, 32, 64);
    acc.y += __shfl_xor(acc.y, 32, 64);
    acc.z += __shfl_xor(acc.z, 32, 64);
    acc.w += __shfl_xor(acc.w, 32, 64);

    if (eslot == 0) {
        ushort4 sv = *(const ushort4*)&hs[(size_t)node * 64 + cq * 4];
        float4 sf = bf4(sv);
        float dn = dis[node];
        float4 bb = *(const float4*)&bias[cq * 4];
        float4 v;
        v.x = dn * (acc.x + sf.x) + bb.x;
        v.y = dn * (acc.y + sf.y) + bb.y;
        v.z = dn * (acc.z + sf.z) + bb.z;
        v.w = dn * (acc.w + sf.w) + bb.w;
        if (RELU) {
            v.x = fmaxf(v.x, 0.f); v.y = fmaxf(v.y, 0.f);
            v.z = fmaxf(v.z, 0.f); v.w = fmaxf(v.w, 0.f);
        }
        *(float4*)&out[(size_t)node * 64 + cq * 4] = v;
    }
}

// Mean pool: batch is sorted -> register-accumulate runs, one atomic per run.
__global__ __launch_bounds__(256) void k_pool(const float* __restrict__ h,
                                              const int* __restrict__ batch,
                                              float* __restrict__ psum,
                                              float* __restrict__ pcnt, int N) {
    int wave = threadIdx.x >> 6;
    int c = threadIdx.x & 63;
    int n0 = blockIdx.x * 64 + wave * 16;
    if (n0 >= N) return;
    int lim = min(n0 + 16, N);
    float acc = 0.f, cnt = 0.f;
    int curg = -1;
    for (int n = n0; n < lim; ++n) {
        int g = batch[n];
        if (g != curg) {
            if (curg >= 0) {
                atomicAdd(&psum[curg * 64 + c], acc);
                if (c == 0) atomicAdd(&pcnt[curg], cnt);
            }
            curg = g;
            acc = 0.f;
            cnt = 0.f;
        }
        acc += h[(size_t)n * 64 + c];
        cnt += 1.f;
    }
    if (curg >= 0) {
        atomicAdd(&psum[curg * 64 + c], acc);
        if (c == 0) atomicAdd(&pcnt[curg], cnt);
    }
}

__global__ __launch_bounds__(64) void k_head(const float* __restrict__ psum,
                                             const float* __restrict__ pcnt,
                                             const float* __restrict__ Wfc,
                                             const float* __restrict__ bfc,
                                             float* __restrict__ out) {
    __shared__ float p[64];
    int g = blockIdx.x, t = threadIdx.x;
    float cnt = fmaxf(pcnt[g], 1.0f);
    p[t] = psum[g * 64 + t] / cnt;
    __syncthreads();
    if (t < 10) {
        float acc = bfc[t];
#pragma unroll
        for (int hh = 0; hh < 64; ++hh) acc += p[hh] * Wfc[hh * 10 + t];
        out[g * 10 + t] = acc;
    }
}

extern "C" void kernel_launch(void* const* d_in, const int* in_sizes, int n_in,
                              void* d_out, int out_size, void* d_ws, size_t ws_size,
                              hipStream_t stream) {
    const float* x = (const float*)d_in[0];
    const int* eidx = (const int*)d_in[1];
    const int* batch = (const int*)d_in[2];
    const float* W1 = (const float*)d_in[3];
    const float* b1 = (const float*)d_in[4];
    const float* W2 = (const float*)d_in[5];
    const float* b2 = (const float*)d_in[6];
    const float* W3 = (const float*)d_in[7];
    const float* b3 = (const float*)d_in[8];
    const float* Wfc = (const float*)d_in[9];
    const float* bfc = (const float*)d_in[10];
    float* out = (float*)d_out;

    const int N = in_sizes[0] / 128;  // 100000
    const int E = in_sizes[1] / 2;    // 3200000
    const int G = out_size / 10;      // 512
    const int NB = (N + 127) / 128;   // 782
    const int chunk = (E + NBLK - 1) / NBLK;

    char* ws = (char*)d_ws;
    size_t off = 0;
    auto alloc = [&](size_t bytes) -> char* {
        char* p = ws + off;
        off = (off + bytes + 511) & ~(size_t)511;
        return p;
    };
    int* deg = (int*)alloc((size_t)N * 4);
    int* rowptr = (int*)alloc((size_t)N * 4);
    float* dis = (float*)alloc((size_t)N * 4);
    int* starts = (int*)alloc((size_t)(MAXNB + 1) * 4);
    int* btotal = (int*)alloc((size_t)MAXNB * 4);
    int* blockhist = (int*)alloc((size_t)NB * NBLK * 4);
    unsigned int* epart = (unsigned int*)alloc((size_t)E * 4);
    int* colidx = (int*)alloc(((size_t)E + (size_t)NB * BPAD) * 4);
    unsigned short* hsb = (unsigned short*)alloc((size_t)(N + 1) * 64 * 2);  // bf16, +dummy row
    float* obuf = (float*)alloc((size_t)N * 64 * 4);
    float* psum = (float*)alloc((size_t)G * 64 * 4 + (size_t)G * 4);
    float* pcnt = psum + (size_t)G * 64;

    hipMemsetAsync(psum, 0, (size_t)G * 64 * 4 + (size_t)G * 4, stream);
    hipMemsetAsync(hsb + (size_t)N * 64, 0, 64 * 2, stream);  // zero dummy row

    const int* esrc = eidx;
    const int* edst = eidx + E;

    k_hist<<<NBLK, 256, 0, stream>>>(edst, blockhist, E, chunk, NB);
    k_bscan<<<NB, 256, 0, stream>>>(blockhist, btotal);
    k_sscan<<<1, 256, 0, stream>>>(btotal, starts, NB);
    k_part<<<NBLK, 256, 0, stream>>>(esrc, edst, blockhist, starts, epart, E, chunk, NB);
    k_fine<<<NB, 256, 0, stream>>>(epart, starts, deg, rowptr, dis, colidx, N);

    int gblk = (N + 63) / 64;
    k_gemm<128><<<gblk, 256, 0, stream>>>(x, W1, dis, hsb, N);
    k_agg<1><<<(N + 3) / 4, 256, 0, stream>>>(hsb, rowptr, deg, colidx, dis, b1, obuf, N);
    k_gemm<64><<<gblk, 256, 0, stream>>>(obuf, W2, dis, hsb, N);
    k_agg<1><<<(N + 3) / 4, 256, 0, stream>>>(hsb, rowptr, deg, colidx, dis, b2, obuf, N);
    k_gemm<64><<<gblk, 256, 0, stream>>>(obuf, W3, dis, hsb, N);
    k_agg<0><<<(N + 3) / 4, 256, 0, stream>>>(hsb, rowptr, deg, colidx, dis, b3, obuf, N);

    k_pool<<<(N + 63) / 64, 256, 0, stream>>>(obuf, batch, psum, pcnt, N);
    k_head<<<G, 64, 0, stream>>>(psum, pcnt, Wfc, bfc, out);
}

// Round 7
// 401.046 us; speedup vs baseline: 10.5623x; 1.0671x over previous
//
#include <hip/hip_runtime.h>
#include <hip/hip_bf16.h>

// ---------------------------------------------------------------------------
// GCN forward: hierarchical atomic-free CSR build (16-padded per-node lists)
// -> 3x (MFMA-bf16 GEMM w/ fused dis-scale + bf16 store -> padded colidx
// gather aggregate) -> run-fused mean pool -> FC head.
// hs = dis[n]*h[n] in bf16 (+zero dummy row N). Inter-layer obuf is bf16.
// GEMM: v_mfma_f32_16x16x32_bf16, A[m=lane&15][k=quad*8+j], Bt staged
// transposed, C/D col=lane&15 row=quad*4+reg (m89-verified layout).
// NOTE (R5 lesson): NO float LDS atomics — CAS loop, ~20x cost.
// ---------------------------------------------------------------------------

#define NBLK 256        // partition blocks
#define MAXNB 1024      // max buckets supported (N <= 131072)
#define FCAP 4608       // LDS edge-staging capacity in k_fine
#define BPAD 2048       // per-bucket colidx padding slack

typedef __attribute__((ext_vector_type(8))) short short8;    // 8 bf16 (4 VGPR)
typedef __attribute__((ext_vector_type(4))) float floatx4;   // MFMA acc

__device__ __forceinline__ float bf2f(unsigned short v) {
    return __uint_as_float(((unsigned int)v) << 16);
}
__device__ __forceinline__ unsigned short f2bf(float x) {
    __hip_bfloat16 b = __float2bfloat16(x);  // round-to-nearest
    return *(unsigned short*)&b;
}
__device__ __forceinline__ float4 bf4(ushort4 v) {
    return make_float4(bf2f(v.x), bf2f(v.y), bf2f(v.z), bf2f(v.w));
}

// P1: per-block bucket histogram (int4-vectorized edge reads).
__global__ __launch_bounds__(256) void k_hist(const int* __restrict__ dst,
                                              int* __restrict__ blockhist,
                                              int E, int chunk, int nb) {
    __shared__ int h[MAXNB];
    int b = blockIdx.x, t = threadIdx.x;
    for (int j = t; j < nb; j += 256) h[j] = 0;
    __syncthreads();
    int lo = b * chunk, hi = min(lo + chunk, E);
    int m = hi - lo;
    int nv = m >> 2;
    const int4* d4 = (const int4*)(dst + lo);
    for (int i = t; i < nv; i += 256) {
        int4 v = d4[i];
        atomicAdd(&h[v.x >> 7], 1);
        atomicAdd(&h[v.y >> 7], 1);
        atomicAdd(&h[v.z >> 7], 1);
        atomicAdd(&h[v.w >> 7], 1);
    }
    for (int i = lo + (nv << 2) + t; i < hi; i += 256) atomicAdd(&h[dst[i] >> 7], 1);
    __syncthreads();
    for (int j = t; j < nb; j += 256) blockhist[j * NBLK + b] = h[j];
}

// P2a: per-bucket exclusive scan over blocks (in place); btotal[j] = total.
__global__ __launch_bounds__(256) void k_bscan(int* __restrict__ blockhist,
                                               int* __restrict__ btotal) {
    __shared__ int sm[256];
    int j = blockIdx.x, t = threadIdx.x;
    int v = blockhist[j * NBLK + t];
    sm[t] = v;
    __syncthreads();
    for (int d = 1; d < 256; d <<= 1) {
        int u = (t >= d) ? sm[t - d] : 0;
        __syncthreads();
        sm[t] += u;
        __syncthreads();
    }
    blockhist[j * NBLK + t] = sm[t] - v;
    if (t == 255) btotal[j] = sm[255];
}

// P2b: single-block exclusive scan of bucket totals -> starts[0..nb].
__global__ __launch_bounds__(256) void k_sscan(const int* __restrict__ btotal,
                                               int* __restrict__ starts, int nb) {
    __shared__ int sm[256];
    int t = threadIdx.x;
    int base = t * 4;
    int v0 = (base + 0 < nb) ? btotal[base + 0] : 0;
    int v1 = (base + 1 < nb) ? btotal[base + 1] : 0;
    int v2 = (base + 2 < nb) ? btotal[base + 2] : 0;
    int v3 = (base + 3 < nb) ? btotal[base + 3] : 0;
    int tsum = v0 + v1 + v2 + v3;
    sm[t] = tsum;
    __syncthreads();
    for (int d = 1; d < 256; d <<= 1) {
        int u = (t >= d) ? sm[t - d] : 0;
        __syncthreads();
        sm[t] += u;
        __syncthreads();
    }
    int excl = sm[t] - tsum;
    if (base + 0 < nb) starts[base + 0] = excl;
    if (base + 1 < nb) starts[base + 1] = excl + v0;
    if (base + 2 < nb) starts[base + 2] = excl + v0 + v1;
    if (base + 3 < nb) starts[base + 3] = excl + v0 + v1 + v2;
    if (t == 255) starts[nb] = sm[255];
}

// P3: partition edges into bucket regions. epart = src | (dst&127)<<17.
__global__ __launch_bounds__(256) void k_part(const int* __restrict__ src,
                                              const int* __restrict__ dst,
                                              const int* __restrict__ blockhist,
                                              const int* __restrict__ starts,
                                              unsigned int* __restrict__ epart,
                                              int E, int chunk, int nb) {
    __shared__ int cur[MAXNB];
    int b = blockIdx.x, t = threadIdx.x;
    for (int j = t; j < nb; j += 256) cur[j] = starts[j] + blockhist[j * NBLK + b];
    __syncthreads();
    int lo = b * chunk, hi = min(lo + chunk, E);
    int m = hi - lo;
    int nv = m >> 2;
    const int4* d4 = (const int4*)(dst + lo);
    const int4* s4 = (const int4*)(src + lo);
    for (int i = t; i < nv; i += 256) {
        int4 d = d4[i];
        int4 s = s4[i];
        int p;
        p = atomicAdd(&cur[d.x >> 7], 1); epart[p] = (unsigned int)s.x | ((unsigned int)(d.x & 127) << 17);
        p = atomicAdd(&cur[d.y >> 7], 1); epart[p] = (unsigned int)s.y | ((unsigned int)(d.y & 127) << 17);
        p = atomicAdd(&cur[d.z >> 7], 1); epart[p] = (unsigned int)s.z | ((unsigned int)(d.z & 127) << 17);
        p = atomicAdd(&cur[d.w >> 7], 1); epart[p] = (unsigned int)s.w | ((unsigned int)(d.w & 127) << 17);
    }
    for (int i = lo + (nv << 2) + t; i < hi; i += 256) {
        int d = dst[i];
        int pos = atomicAdd(&cur[d >> 7], 1);
        epart[pos] = (unsigned int)src[i] | ((unsigned int)(d & 127) << 17);
    }
}

// P4: per-bucket fine sort with padded per-node lists (pad src = N).
__global__ __launch_bounds__(256) void k_fine(const unsigned int* __restrict__ epart,
                                              const int* __restrict__ starts,
                                              int* __restrict__ deg,
                                              int* __restrict__ rowptr,
                                              float* __restrict__ dis,
                                              int* __restrict__ colidx, int N) {
    __shared__ unsigned int eb[FCAP];
    __shared__ int cnt[128], sc[128], cur[128];
    int j = blockIdx.x, t = threadIdx.x;
    int n0 = j << 7;
    int nn = min(128, N - n0);
    int s = starts[j], e = starts[j + 1];
    int m = e - s;
    int pbase = s + j * BPAD;
    if (t < 128) cnt[t] = 0;
    __syncthreads();
    for (int i = t; i < m; i += 256) {
        unsigned int p = epart[s + i];
        if (i < FCAP) eb[i] = p;
        atomicAdd(&cnt[p >> 17], 1);
    }
    __syncthreads();
    int pcv = 0;
    if (t < 128) { pcv = (cnt[t] + 15) & ~15; sc[t] = pcv; }
    __syncthreads();
    for (int d = 1; d < 128; d <<= 1) {
        int u = (t < 128 && t >= d) ? sc[t - d] : 0;
        __syncthreads();
        if (t < 128) sc[t] += u;
        __syncthreads();
    }
    if (t < nn) {
        int c = cnt[t];
        int rp = pbase + sc[t] - pcv;
        deg[n0 + t] = c;
        rowptr[n0 + t] = rp;
        dis[n0 + t] = rsqrtf((float)c + 1.0f);
        cur[t] = rp;
    }
    __syncthreads();
    for (int i = t; i < m; i += 256) {
        unsigned int p = (i < FCAP) ? eb[i] : epart[s + i];
        int pos = atomicAdd(&cur[p >> 17], 1);
        colidx[pos] = (int)(p & 0x1FFFF);
    }
    __syncthreads();
    if (t < nn) {
        int endp = rowptr[n0 + t] + ((cnt[t] + 15) & ~15);
        for (int q = cur[t]; q < endp; ++q) colidx[q] = N;  // dummy row
    }
}

// MFMA GEMM: C[64x64] per block = A[64xK] * W[Kx64]; bf16 inputs, fp32 acc.
// 4 waves; wave w does rows w*16..w*16+15, all 4 col-tiles. Epilogue scales
// by dis[row], stores bf16 hs. ABF16: A already bf16; else fp32->bf16 cast.
template <int K, int ABF16>
__global__ __launch_bounds__(256) void k_gemm_mfma(const void* __restrict__ Ap,
                                                   const float* __restrict__ W,
                                                   const float* __restrict__ dis,
                                                   unsigned short* __restrict__ hs,
                                                   int N) {
    constexpr int AS = K + 8;  // LDS row stride (shorts); 2-way bank pattern
    __shared__ unsigned short As[64 * AS];
    __shared__ unsigned short Bt[64 * AS];
    const int tid = threadIdx.x;
    const int r0 = blockIdx.x * 64;

    // stage W [K][64] fp32 -> Bt[n][k] bf16 (transposed)
    for (int idx = tid; idx < K * 64; idx += 256) {
        int k = idx >> 6, n = idx & 63;
        Bt[n * AS + k] = f2bf(W[idx]);
    }
    // stage A -> As[row][k] bf16
    if (ABF16) {
        const unsigned short* A = (const unsigned short*)Ap;
        for (int idx = tid; idx < 64 * (K / 8); idx += 256) {
            int row = idx / (K / 8), c8 = idx % (K / 8);
            int gr = r0 + row;
            uint4 v = (gr < N) ? *(const uint4*)&A[(size_t)gr * K + c8 * 8]
                               : make_uint4(0u, 0u, 0u, 0u);
            *(uint4*)&As[row * AS + c8 * 8] = v;
        }
    } else {
        const float* A = (const float*)Ap;
        for (int idx = tid; idx < 64 * (K / 4); idx += 256) {
            int row = idx / (K / 4), kq = idx % (K / 4);
            int gr = r0 + row;
            float4 a = (gr < N) ? ((const float4*)(A + (size_t)gr * K))[kq]
                                : make_float4(0.f, 0.f, 0.f, 0.f);
            ushort4 v;
            v.x = f2bf(a.x); v.y = f2bf(a.y); v.z = f2bf(a.z); v.w = f2bf(a.w);
            *(ushort4*)&As[row * AS + kq * 4] = v;
        }
    }
    __syncthreads();

    const int w = tid >> 6, lane = tid & 63;
    const int m = lane & 15, quad = lane >> 4;
    floatx4 acc0 = {0.f, 0.f, 0.f, 0.f};
    floatx4 acc1 = {0.f, 0.f, 0.f, 0.f};
    floatx4 acc2 = {0.f, 0.f, 0.f, 0.f};
    floatx4 acc3 = {0.f, 0.f, 0.f, 0.f};
#pragma unroll
    for (int s = 0; s < K / 32; ++s) {
        int ko = s * 32 + quad * 8;
        short8 a  = *(const short8*)&As[(w * 16 + m) * AS + ko];
        short8 b0 = *(const short8*)&Bt[(0 * 16 + m) * AS + ko];
        short8 b1 = *(const short8*)&Bt[(1 * 16 + m) * AS + ko];
        short8 b2 = *(const short8*)&Bt[(2 * 16 + m) * AS + ko];
        short8 b3 = *(const short8*)&Bt[(3 * 16 + m) * AS + ko];
        acc0 = __builtin_amdgcn_mfma_f32_16x16x32_bf16(a, b0, acc0, 0, 0, 0);
        acc1 = __builtin_amdgcn_mfma_f32_16x16x32_bf16(a, b1, acc1, 0, 0, 0);
        acc2 = __builtin_amdgcn_mfma_f32_16x16x32_bf16(a, b2, acc2, 0, 0, 0);
        acc3 = __builtin_amdgcn_mfma_f32_16x16x32_bf16(a, b3, acc3, 0, 0, 0);
    }
#pragma unroll
    for (int r = 0; r < 4; ++r) {
        int gr = r0 + w * 16 + quad * 4 + r;
        if (gr < N) {
            float dn = dis[gr];
            size_t base = (size_t)gr * 64 + m;
            hs[base + 0]  = f2bf(acc0[r] * dn);
            hs[base + 16] = f2bf(acc1[r] * dn);
            hs[base + 32] = f2bf(acc2[r] * dn);
            hs[base + 48] = f2bf(acc3[r] * dn);
        }
    }
}

// One wave per node. lane = eslot(0..3) x chquad(0..15). Padded x16 lists,
// branchless 16/32-edge blocks. OUTBF: write bf16 (inter-layer) or fp32.
template <int RELU, int OUTBF>
__global__ __launch_bounds__(256) void k_agg(const unsigned short* __restrict__ hs,
                                             const int* __restrict__ rowptr,
                                             const int* __restrict__ deg,
                                             const int* __restrict__ colidx,
                                             const float* __restrict__ dis,
                                             const float* __restrict__ bias,
                                             void* __restrict__ outp, int N) {
    int node = blockIdx.x * 4 + (threadIdx.x >> 6);
    if (node >= N) return;
    int lane = threadIdx.x & 63;
    int eslot = lane >> 4;
    int cq = lane & 15;

    int start = rowptr[node];
    int cnt = deg[node];
    int pcnt = (cnt + 15) & ~15;
    const int* ci = colidx + start + eslot;
    float4 acc = make_float4(0.f, 0.f, 0.f, 0.f);

    int i = 0;
    if (pcnt & 16) {
        int s0 = ci[0], s1 = ci[4], s2 = ci[8], s3 = ci[12];
        ushort4 a0 = *(const ushort4*)&hs[(size_t)s0 * 64 + cq * 4];
        ushort4 a1 = *(const ushort4*)&hs[(size_t)s1 * 64 + cq * 4];
        ushort4 a2 = *(const ushort4*)&hs[(size_t)s2 * 64 + cq * 4];
        ushort4 a3 = *(const ushort4*)&hs[(size_t)s3 * 64 + cq * 4];
        float4 f0 = bf4(a0), f1 = bf4(a1), f2 = bf4(a2), f3 = bf4(a3);
        acc.x += f0.x + f1.x + f2.x + f3.x;
        acc.y += f0.y + f1.y + f2.y + f3.y;
        acc.z += f0.z + f1.z + f2.z + f3.z;
        acc.w += f0.w + f1.w + f2.w + f3.w;
        i = 16;
    }
    for (; i < pcnt; i += 32) {
        int s0 = ci[i + 0],  s1 = ci[i + 4],  s2 = ci[i + 8],  s3 = ci[i + 12];
        int s4 = ci[i + 16], s5 = ci[i + 20], s6 = ci[i + 24], s7 = ci[i + 28];
        ushort4 a0 = *(const ushort4*)&hs[(size_t)s0 * 64 + cq * 4];
        ushort4 a1 = *(const ushort4*)&hs[(size_t)s1 * 64 + cq * 4];
        ushort4 a2 = *(const ushort4*)&hs[(size_t)s2 * 64 + cq * 4];
        ushort4 a3 = *(const ushort4*)&hs[(size_t)s3 * 64 + cq * 4];
        ushort4 a4 = *(const ushort4*)&hs[(size_t)s4 * 64 + cq * 4];
        ushort4 a5 = *(const ushort4*)&hs[(size_t)s5 * 64 + cq * 4];
        ushort4 a6 = *(const ushort4*)&hs[(size_t)s6 * 64 + cq * 4];
        ushort4 a7 = *(const ushort4*)&hs[(size_t)s7 * 64 + cq * 4];
        float4 f0 = bf4(a0), f1 = bf4(a1), f2 = bf4(a2), f3 = bf4(a3);
        float4 f4 = bf4(a4), f5 = bf4(a5), f6 = bf4(a6), f7 = bf4(a7);
        acc.x += (f0.x + f1.x) + (f2.x + f3.x) + (f4.x + f5.x) + (f6.x + f7.x);
        acc.y += (f0.y + f1.y) + (f2.y + f3.y) + (f4.y + f5.y) + (f6.y + f7.y);
        acc.z += (f0.z + f1.z) + (f2.z + f3.z) + (f4.z + f5.z) + (f6.z + f7.z);
        acc.w += (f0.w + f1.w) + (f2.w + f3.w) + (f4.w + f5.w) + (f6.w + f7.w);
    }

    acc.x += __shfl_xor(acc.x, 16, 64);
    acc.y += __shfl_xor(acc.y, 16, 64);
    acc.z += __shfl_xor(acc.z, 16, 64);
    acc.w += __shfl_xor(acc.w, 16, 64);
    acc.x += __shfl_xor(acc.x, 32, 64);
    acc.y += __shfl_xor(acc.y, 32, 64);
    acc.z += __shfl_xor(acc.z, 32, 64);
    acc.w += __shfl_xor(acc.w, 32, 64);

    if (eslot == 0) {
        ushort4 sv = *(const ushort4*)&hs[(size_t)node * 64 + cq * 4];
        float4 sf = bf4(sv);
        float dn = dis[node];
        float4 bb = *(const float4*)&bias[cq * 4];
        float4 v;
        v.x = dn * (acc.x + sf.x) + bb.x;
        v.y = dn * (acc.y + sf.y) + bb.y;
        v.z = dn * (acc.z + sf.z) + bb.z;
        v.w = dn * (acc.w + sf.w) + bb.w;
        if (RELU) {
            v.x = fmaxf(v.x, 0.f); v.y = fmaxf(v.y, 0.f);
            v.z = fmaxf(v.z, 0.f); v.w = fmaxf(v.w, 0.f);
        }
        if (OUTBF) {
            ushort4 o;
            o.x = f2bf(v.x); o.y = f2bf(v.y); o.z = f2bf(v.z); o.w = f2bf(v.w);
            *(ushort4*)&((unsigned short*)outp)[(size_t)node * 64 + cq * 4] = o;
        } else {
            *(float4*)&((float*)outp)[(size_t)node * 64 + cq * 4] = v;
        }
    }
}

// Mean pool: batch is sorted -> register-accumulate runs, one atomic per run.
__global__ __launch_bounds__(256) void k_pool(const float* __restrict__ h,
                                              const int* __restrict__ batch,
                                              float* __restrict__ psum,
                                              float* __restrict__ pcnt, int N) {
    int wave = threadIdx.x >> 6;
    int c = threadIdx.x & 63;
    int n0 = blockIdx.x * 64 + wave * 16;
    if (n0 >= N) return;
    int lim = min(n0 + 16, N);
    float acc = 0.f, cnt = 0.f;
    int curg = -1;
    for (int n = n0; n < lim; ++n) {
        int g = batch[n];
        if (g != curg) {
            if (curg >= 0) {
                atomicAdd(&psum[curg * 64 + c], acc);
                if (c == 0) atomicAdd(&pcnt[curg], cnt);
            }
            curg = g;
            acc = 0.f;
            cnt = 0.f;
        }
        acc += h[(size_t)n * 64 + c];
        cnt += 1.f;
    }
    if (curg >= 0) {
        atomicAdd(&psum[curg * 64 + c], acc);
        if (c == 0) atomicAdd(&pcnt[curg], cnt);
    }
}

__global__ __launch_bounds__(64) void k_head(const float* __restrict__ psum,
                                             const float* __restrict__ pcnt,
                                             const float* __restrict__ Wfc,
                                             const float* __restrict__ bfc,
                                             float* __restrict__ out) {
    __shared__ float p[64];
    int g = blockIdx.x, t = threadIdx.x;
    float cnt = fmaxf(pcnt[g], 1.0f);
    p[t] = psum[g * 64 + t] / cnt;
    __syncthreads();
    if (t < 10) {
        float acc = bfc[t];
#pragma unroll
        for (int hh = 0; hh < 64; ++hh) acc += p[hh] * Wfc[hh * 10 + t];
        out[g * 10 + t] = acc;
    }
}

extern "C" void kernel_launch(void* const* d_in, const int* in_sizes, int n_in,
                              void* d_out, int out_size, void* d_ws, size_t ws_size,
                              hipStream_t stream) {
    const float* x = (const float*)d_in[0];
    const int* eidx = (const int*)d_in[1];
    const int* batch = (const int*)d_in[2];
    const float* W1 = (const float*)d_in[3];
    const float* b1 = (const float*)d_in[4];
    const float* W2 = (const float*)d_in[5];
    const float* b2 = (const float*)d_in[6];
    const float* W3 = (const float*)d_in[7];
    const float* b3 = (const float*)d_in[8];
    const float* Wfc = (const float*)d_in[9];
    const float* bfc = (const float*)d_in[10];
    float* out = (float*)d_out;

    const int N = in_sizes[0] / 128;  // 100000
    const int E = in_sizes[1] / 2;    // 3200000
    const int G = out_size / 10;      // 512
    const int NB = (N + 127) / 128;   // 782
    const int chunk = (E + NBLK - 1) / NBLK;

    char* ws = (char*)d_ws;
    size_t off = 0;
    auto alloc = [&](size_t bytes) -> char* {
        char* p = ws + off;
        off = (off + bytes + 511) & ~(size_t)511;
        return p;
    };
    int* deg = (int*)alloc((size_t)N * 4);
    int* rowptr = (int*)alloc((size_t)N * 4);
    float* dis = (float*)alloc((size_t)N * 4);
    int* starts = (int*)alloc((size_t)(MAXNB + 1) * 4);
    int* btotal = (int*)alloc((size_t)MAXNB * 4);
    int* blockhist = (int*)alloc((size_t)NB * NBLK * 4);
    unsigned int* epart = (unsigned int*)alloc((size_t)E * 4);
    int* colidx = (int*)alloc(((size_t)E + (size_t)NB * BPAD) * 4);
    unsigned short* hsb = (unsigned short*)alloc((size_t)(N + 1) * 64 * 2);  // +dummy row
    float* obuf = (float*)alloc((size_t)N * 64 * 4);  // fp32 for agg3; bf16 view earlier
    unsigned short* obufb = (unsigned short*)obuf;
    float* psum = (float*)alloc((size_t)G * 64 * 4 + (size_t)G * 4);
    float* pcnt = psum + (size_t)G * 64;

    hipMemsetAsync(psum, 0, (size_t)G * 64 * 4 + (size_t)G * 4, stream);
    hipMemsetAsync(hsb + (size_t)N * 64, 0, 64 * 2, stream);  // zero dummy row

    const int* esrc = eidx;
    const int* edst = eidx + E;

    k_hist<<<NBLK, 256, 0, stream>>>(edst, blockhist, E, chunk, NB);
    k_bscan<<<NB, 256, 0, stream>>>(blockhist, btotal);
    k_sscan<<<1, 256, 0, stream>>>(btotal, starts, NB);
    k_part<<<NBLK, 256, 0, stream>>>(esrc, edst, blockhist, starts, epart, E, chunk, NB);
    k_fine<<<NB, 256, 0, stream>>>(epart, starts, deg, rowptr, dis, colidx, N);

    int gblk = (N + 63) / 64;
    k_gemm_mfma<128, 0><<<gblk, 256, 0, stream>>>(x, W1, dis, hsb, N);
    k_agg<1, 1><<<(N + 3) / 4, 256, 0, stream>>>(hsb, rowptr, deg, colidx, dis, b1, obufb, N);
    k_gemm_mfma<64, 1><<<gblk, 256, 0, stream>>>(obufb, W2, dis, hsb, N);
    k_agg<1, 1><<<(N + 3) / 4, 256, 0, stream>>>(hsb, rowptr, deg, colidx, dis, b2, obufb, N);
    k_gemm_mfma<64, 1><<<gblk, 256, 0, stream>>>(obufb, W3, dis, hsb, N);
    k_agg<0, 0><<<(N + 3) / 4, 256, 0, stream>>>(hsb, rowptr, deg, colidx, dis, b3, obuf, N);

    k_pool<<<(N + 63) / 64, 256, 0, stream>>>(obuf, batch, psum, pcnt, N);
    k_head<<<G, 64, 0, stream>>>(psum, pcnt, Wfc, bfc, out);
}